// Round 10
// baseline (3830.058 us; speedup 1.0000x reference)
//
#include <hip/hip_runtime.h>
#include <math.h>

namespace {
constexpr int N_ = 50000;
constexpr int E_ = 400000;
constexpr int F_ = 32;
constexpr int K_ = 16;
constexpr int B_ = 10;
constexpr float CUT_ = 10.0f;
constexpr float EPS_ = 1e-8f;
constexpr size_t WS_FLOATS = 161000000;  // ~644 MB (incl. o_* checkpoint)
}

// Static device scratch (d_ws size unknown).
__device__ float g_ws[WS_FLOATS];

__constant__ float c_binom[K_] = {1.f,15.f,105.f,455.f,1365.f,3003.f,5005.f,6435.f,
                                  6435.f,5005.f,3003.f,1365.f,455.f,105.f,15.f,1.f};

__device__ __forceinline__ float sigm(float x) { return 1.f / (1.f + expf(-x)); }

// ---------------- utility fills ----------------
__global__ void fill_kernel(float* __restrict__ p, size_t n, float v) {
  size_t i = (size_t)blockIdx.x * blockDim.x + threadIdx.x;
  size_t st = (size_t)gridDim.x * blockDim.x;
  for (; i < n; i += st) p[i] = v;
}

__global__ void fill_int_kernel(int* __restrict__ p, size_t n, int v) {
  size_t i = (size_t)blockIdx.x * blockDim.x + threadIdx.x;
  size_t st = (size_t)gridDim.x * blockDim.x;
  for (; i < n; i += st) p[i] = v;
}

__global__ void init_embed_kernel(float* __restrict__ s, const float* __restrict__ embed,
                                  const int* __restrict__ Z) {
  int gid = blockIdx.x * blockDim.x + threadIdx.x;
  int n = gid >> 5, f = gid & 31;
  s[gid] = embed[Z[n] * F_ + f];
}

__global__ void init_gs_kernel(float* __restrict__ Gs, const float* __restrict__ w_out) {
  int gid = blockIdx.x * blockDim.x + threadIdx.x;
  Gs[gid] = -w_out[gid & 31];
}

// ---------------- CSR build ----------------
__global__ void hist_kernel(const int* __restrict__ dst, const int* __restrict__ src,
                            int* __restrict__ cntd, int* __restrict__ cnts) {
  int e = blockIdx.x * blockDim.x + threadIdx.x;
  if (e < E_) { atomicAdd(&cntd[dst[e]], 1); atomicAdd(&cnts[src[e]], 1); }
}

__global__ __launch_bounds__(1024) void scan_kernel(
    const int* __restrict__ cntd, const int* __restrict__ cnts,
    int* __restrict__ offd, int* __restrict__ offs) {
  const int* cnt = blockIdx.x ? cnts : cntd;
  int* off = blockIdx.x ? offs : offd;
  __shared__ int part[1024];
  int tid = threadIdx.x;
  const int CH = (N_ + 1023) / 1024;  // 49
  int base = tid * CH;
  int sum = 0;
  for (int i = 0; i < CH; ++i) { int j = base + i; if (j < N_) sum += cnt[j]; }
  part[tid] = sum; __syncthreads();
  for (int d = 1; d < 1024; d <<= 1) {
    int t = (tid >= d) ? part[tid - d] : 0; __syncthreads();
    part[tid] += t; __syncthreads();
  }
  int run = (tid == 0) ? 0 : part[tid - 1];
  for (int i = 0; i < CH; ++i) {
    int j = base + i;
    if (j <= N_) { off[j] = run; if (j < N_) run += cnt[j]; }
  }
}

__global__ void cursor_init_kernel(const int* __restrict__ offd, const int* __restrict__ offs,
                                   int* __restrict__ curd, int* __restrict__ curs) {
  int i = blockIdx.x * blockDim.x + threadIdx.x;
  if (i < N_) { curd[i] = offd[i]; curs[i] = offs[i]; }
}

__global__ void scatter_kernel(const int* __restrict__ dst, const int* __restrict__ src,
                               int* __restrict__ curd, int* __restrict__ curs,
                               int* __restrict__ permd, int* __restrict__ perms) {
  int e = blockIdx.x * blockDim.x + threadIdx.x;
  if (e < E_) {
    permd[atomicAdd(&curd[dst[e]], 1)] = e;
    perms[atomicAdd(&curs[src[e]], 1)] = e;
  }
}

// ---------------- degree sort (descending), LDS-privatized ----------------
__global__ __launch_bounds__(256) void sort_hist_kernel(
    const int* __restrict__ offd, const int* __restrict__ offs, int* __restrict__ binc) {
  __shared__ int l[128];
  int tid = threadIdx.x;
  if (tid < 128) l[tid] = 0;
  __syncthreads();
  int n = blockIdx.x * 256 + tid;
  if (n < N_) {
    int bd = 63 - min(offd[n+1] - offd[n], 63);
    atomicAdd(&l[bd], 1);
    int bs = 63 - min(offs[n+1] - offs[n], 63);
    atomicAdd(&l[64 + bs], 1);
  }
  __syncthreads();
  if (tid < 128 && l[tid] > 0) atomicAdd(&binc[tid], l[tid]);
}

__global__ void sort_scan_kernel(const int* __restrict__ binc, int* __restrict__ bcur) {
  int t = threadIdx.x;  // 0: dst side, 1: src side
  if (t < 2) {
    int base = t * 64;
    int run = 0;
    for (int i = 0; i < 64; ++i) { bcur[base + i] = run; run += binc[base + i]; }
  }
}

// block-aggregated: LDS rank + one global atomic per (block,bin)
__global__ __launch_bounds__(256) void sort_scatter_kernel(
    const int* __restrict__ offd, const int* __restrict__ offs,
    int* __restrict__ bcur,
    int* __restrict__ ord_d, int* __restrict__ ord_s) {
  __shared__ int lcnt[128];
  __shared__ int lbase[128];
  int tid = threadIdx.x;
  if (tid < 128) lcnt[tid] = 0;
  __syncthreads();
  int n = blockIdx.x * 256 + tid;
  int bd = 0, bs = 0, rkd = 0, rks = 0;
  bool act = (n < N_);
  if (act) {
    bd = 63 - min(offd[n+1] - offd[n], 63);
    rkd = atomicAdd(&lcnt[bd], 1);
    bs = 64 + 63 - min(offs[n+1] - offs[n], 63);
    rks = atomicAdd(&lcnt[bs], 1);
  }
  __syncthreads();
  if (tid < 128 && lcnt[tid] > 0) lbase[tid] = atomicAdd(&bcur[tid], lcnt[tid]);
  __syncthreads();
  if (act) {
    ord_d[lbase[bd] + rkd] = n;
    ord_s[lbase[bs] + rks] = n;
  }
}

// ---------------- geometry / basis (rad + drad interleaved: rd[e][32]) ----------------
__global__ void geom_kernel(const float* __restrict__ pos, const int* __restrict__ dst,
                            const int* __restrict__ src, float* __restrict__ rd,
                            float* __restrict__ u3, float* __restrict__ rr) {
  int e = blockIdx.x * blockDim.x + threadIdx.x;
  if (e >= E_) return;
  int nd = dst[e], ns = src[e];
  float dx = pos[ns*3+0] - pos[nd*3+0];
  float dy = pos[ns*3+1] - pos[nd*3+1];
  float dz = pos[ns*3+2] - pos[nd*3+2];
  float r = sqrtf(dx*dx + dy*dy + dz*dz + EPS_);
  float t = r / (1.f + r);
  float b = 1.f - t;
  float tp[K_], bp[K_];
  tp[0] = 1.f; bp[0] = 1.f;
#pragma unroll
  for (int k = 1; k < K_; ++k) { tp[k] = tp[k-1]*t; bp[k] = bp[k-1]*b; }
  float cut = 0.f, dcut = 0.f;
  if (r < CUT_) {
    float den = (CUT_ - r) * (CUT_ + r);
    cut = expf(-r*r/den);
    dcut = cut * (-2.f*r*CUT_*CUT_/(den*den));
  }
  float inv1pr = 1.f / (1.f + r);
  float dtdr = inv1pr * inv1pr;
#pragma unroll
  for (int k = 0; k < K_; ++k) {
    float rrk = c_binom[k]*tp[k]*bp[K_-1-k];
    float d1 = (k > 0) ? k*tp[k-1]*bp[K_-1-k] : 0.f;
    float d2 = (k < K_-1) ? (K_-1-k)*tp[k]*bp[K_-2-k] : 0.f;
    float drdt = c_binom[k]*(d1 - d2);
    rd[(size_t)e*32 + k]      = rrk*cut;                     // rad_k
    rd[(size_t)e*32 + 16 + k] = drdt*dtdr*cut + rrk*dcut;    // d(rad_k)/dr
  }
  float invr = 1.f / r;
  u3[(size_t)e*3+0] = dx*invr;
  u3[(size_t)e*3+1] = dy*invr;
  u3[(size_t)e*3+2] = dz*invr;
  rr[e] = r;
}

// ---------------- forward edge pass: 32 lanes per dst node, 256-thr blocks ----------------
__global__ __launch_bounds__(256) void edge_fwd_csr(
    const int* __restrict__ ord_d,
    const int* __restrict__ dst_off, const int* __restrict__ dst_perm,
    const int* __restrict__ src,
    const float* __restrict__ rd, const float* __restrict__ u3,
    const float* __restrict__ Wb0, const float* __restrict__ Wb1, const float* __restrict__ pw,
    const float* __restrict__ s, const float* __restrict__ v,
    const float* __restrict__ ps, const float* __restrict__ pv,
    float* __restrict__ ys, float* __restrict__ yv,
    float* __restrict__ yps, float* __restrict__ ypv) {
  int gid = blockIdx.x * 256 + threadIdx.x;
  int n = ord_d[gid >> 5];
  int f = gid & 31;
  float wb0[K_], wb1[K_];
#pragma unroll
  for (int k = 0; k < K_; ++k) { wb0[k] = Wb0[k*F_+f]; wb1[k] = Wb1[k*F_+f]; }
  float pw0=pw[f],      pw1=pw[F_+f],   pw2=pw[2*F_+f], pw3=pw[3*F_+f], pw4=pw[4*F_+f];
  float pw5=pw[5*F_+f], pw6=pw[6*F_+f], pw7=pw[7*F_+f], pw8=pw[8*F_+f], pw9=pw[9*F_+f];
  float ms=0.f, mps=0.f, mv0=0.f, mv1=0.f, mv2=0.f, mpv0=0.f, mpv1=0.f, mpv2=0.f;
  int j0 = dst_off[n], j1 = dst_off[n+1];
  for (int j = j0; j < j1; ++j) {
    int e = dst_perm[j];
    int ns = src[e];
    float radl = (f < K_) ? rd[(size_t)e*32 + f] : 0.f;
    float q0 = 0.f, q1 = 0.f;
#pragma unroll
    for (int k = 0; k < K_; ++k) {
      float rk = __shfl(radl, k, 32);
      q0 += rk * wb0[k];
      q1 += rk * wb1[k];
    }
    float u0 = u3[(size_t)e*3+0], u1 = u3[(size_t)e*3+1], u2 = u3[(size_t)e*3+2];
    size_t sb = (size_t)ns*F_, vb = (size_t)ns*3*F_;
    float se = s[sb+f], pse = ps[sb+f];
    float ve0 = v[vb+f], ve1 = v[vb+F_+f], ve2 = v[vb+2*F_+f];
    float pve0 = pv[vb+f], pve1 = pv[vb+F_+f], pve2 = pv[vb+2*F_+f];
    float vu  = ve0*u0 + ve1*u1 + ve2*u2;
    float pvu = pve0*u0 + pve1*u1 + pve2*u2;
    float cpu0 = pve1*u2 - pve2*u1, cpu1 = pve2*u0 - pve0*u2, cpu2 = pve0*u1 - pve1*u0;
    float cvu0 = ve1*u2 - ve2*u1,  cvu1 = ve2*u0 - ve0*u2,  cvu2 = ve0*u1 - ve1*u0;
    ms  += pw0*se*q0  + pw1*vu*q1;
    mps += pw2*pse*q0 + pw3*pvu*q1;
    mv0 += pw4*ve0*q0 + (pw5*se*u0 + pw6*cpu0)*q1;
    mv1 += pw4*ve1*q0 + (pw5*se*u1 + pw6*cpu1)*q1;
    mv2 += pw4*ve2*q0 + (pw5*se*u2 + pw6*cpu2)*q1;
    mpv0 += pw7*pve0*q0 + (pw8*pse*u0 + pw9*cvu0)*q1;
    mpv1 += pw7*pve1*q0 + (pw8*pse*u1 + pw9*cvu1)*q1;
    mpv2 += pw7*pve2*q0 + (pw8*pse*u2 + pw9*cvu2)*q1;
  }
  size_t db = (size_t)n*F_, dvb = (size_t)n*3*F_;
  ys[db+f] = ms;
  yps[db+f] = mps;
  yv[dvb+f] = mv0;   yv[dvb+F_+f] = mv1;   yv[dvb+2*F_+f] = mv2;
  ypv[dvb+f] = mpv0; ypv[dvb+F_+f] = mpv1; ypv[dvb+2*F_+f] = mpv2;
}

// ---------------- forward node MLP: 2 nodes/thread, stores a_* and o_* ----------------
__global__ __launch_bounds__(256) void node_fwd_kernel(
    float* __restrict__ s, float* __restrict__ v, float* __restrict__ ps, float* __restrict__ pv,
    const float* __restrict__ ys, const float* __restrict__ yv,
    const float* __restrict__ yps, const float* __restrict__ ypv,
    const float* __restrict__ W1, const float* __restrict__ b1v,
    const float* __restrict__ W2, const float* __restrict__ b2v,
    float* __restrict__ a_s, float* __restrict__ a_v,
    float* __restrict__ a_ps, float* __restrict__ a_pv,
    float* __restrict__ o_s, float* __restrict__ o_v,
    float* __restrict__ o_ps, float* __restrict__ o_pv) {
  int t = threadIdx.x;
  int f = t & 31, g = t >> 5;
  int nA = blockIdx.x * 16 + g;
  int nB = nA + 8;
  size_t iA = (size_t)nA*F_ + f, iB = (size_t)nB*F_ + f;
  size_t vA = (size_t)nA*3*F_ + f, vB = (size_t)nB*3*F_ + f;
  float As  = s[iA] + ys[iA],        Bs  = s[iB] + ys[iB];
  float Av0 = v[vA] + yv[vA],        Bv0 = v[vB] + yv[vB];
  float Av1 = v[vA+F_] + yv[vA+F_],  Bv1 = v[vB+F_] + yv[vB+F_];
  float Av2 = v[vA+2*F_]+yv[vA+2*F_],Bv2 = v[vB+2*F_]+yv[vB+2*F_];
  float Aps = ps[iA] + yps[iA],      Bps = ps[iB] + yps[iB];
  float Ap0 = pv[vA] + ypv[vA],      Bp0 = pv[vB] + ypv[vB];
  float Ap1 = pv[vA+F_]+ypv[vA+F_],  Bp1 = pv[vB+F_]+ypv[vB+F_];
  float Ap2 = pv[vA+2*F_]+ypv[vA+2*F_], Bp2 = pv[vB+2*F_]+ypv[vB+2*F_];
  const float* W1s = W1; const float* W1v = W1 + F_*F_;
  const float* W1p = W1 + 2*F_*F_; const float* W1q = W1 + 3*F_*F_;
  float b1f = b1v[f];
  float aAs=b1f, aAv0=0.f, aAv1=0.f, aAv2=0.f, aAps=0.f, aAp0=0.f, aAp1=0.f, aAp2=0.f;
  float aBs=b1f, aBv0=0.f, aBv1=0.f, aBv2=0.f, aBps=0.f, aBp0=0.f, aBp1=0.f, aBp2=0.f;
#pragma unroll
  for (int fp = 0; fp < F_; ++fp) {
    float w_s = W1s[fp*F_+f], w_v = W1v[fp*F_+f], w_p = W1p[fp*F_+f], w_q = W1q[fp*F_+f];
    aAs  += __shfl(As, fp, 32)*w_s;   aBs  += __shfl(Bs, fp, 32)*w_s;
    aAv0 += __shfl(Av0, fp, 32)*w_v;  aBv0 += __shfl(Bv0, fp, 32)*w_v;
    aAv1 += __shfl(Av1, fp, 32)*w_v;  aBv1 += __shfl(Bv1, fp, 32)*w_v;
    aAv2 += __shfl(Av2, fp, 32)*w_v;  aBv2 += __shfl(Bv2, fp, 32)*w_v;
    aAps += __shfl(Aps, fp, 32)*w_p;  aBps += __shfl(Bps, fp, 32)*w_p;
    aAp0 += __shfl(Ap0, fp, 32)*w_q;  aBp0 += __shfl(Bp0, fp, 32)*w_q;
    aAp1 += __shfl(Ap1, fp, 32)*w_q;  aBp1 += __shfl(Bp1, fp, 32)*w_q;
    aAp2 += __shfl(Ap2, fp, 32)*w_q;  aBp2 += __shfl(Bp2, fp, 32)*w_q;
  }
  a_s[iA]=aAs; a_v[vA]=aAv0; a_v[vA+F_]=aAv1; a_v[vA+2*F_]=aAv2;
  a_ps[iA]=aAps; a_pv[vA]=aAp0; a_pv[vA+F_]=aAp1; a_pv[vA+2*F_]=aAp2;
  a_s[iB]=aBs; a_v[vB]=aBv0; a_v[vB+F_]=aBv1; a_v[vB+2*F_]=aBv2;
  a_ps[iB]=aBps; a_pv[vB]=aBp0; a_pv[vB+F_]=aBp1; a_pv[vB+2*F_]=aBp2;
  float gA = sigm(aAs), gB = sigm(aBs);
  float hAs=aAs*gA, hAv0=aAv0*gA, hAv1=aAv1*gA, hAv2=aAv2*gA;
  float hAps=aAps*gA, hAp0=aAp0*gA, hAp1=aAp1*gA, hAp2=aAp2*gA;
  float hBs=aBs*gB, hBv0=aBv0*gB, hBv1=aBv1*gB, hBv2=aBv2*gB;
  float hBps=aBps*gB, hBp0=aBp0*gB, hBp1=aBp1*gB, hBp2=aBp2*gB;
  const float* W2s = W2; const float* W2v = W2 + F_*F_;
  const float* W2p = W2 + 2*F_*F_; const float* W2q = W2 + 3*F_*F_;
  float b2f = b2v[f];
  float oAs=b2f, oAv0=0.f, oAv1=0.f, oAv2=0.f, oAps=0.f, oAp0=0.f, oAp1=0.f, oAp2=0.f;
  float oBs=b2f, oBv0=0.f, oBv1=0.f, oBv2=0.f, oBps=0.f, oBp0=0.f, oBp1=0.f, oBp2=0.f;
#pragma unroll
  for (int fp = 0; fp < F_; ++fp) {
    float w_s = W2s[fp*F_+f], w_v = W2v[fp*F_+f], w_p = W2p[fp*F_+f], w_q = W2q[fp*F_+f];
    oAs  += __shfl(hAs, fp, 32)*w_s;   oBs  += __shfl(hBs, fp, 32)*w_s;
    oAv0 += __shfl(hAv0, fp, 32)*w_v;  oBv0 += __shfl(hBv0, fp, 32)*w_v;
    oAv1 += __shfl(hAv1, fp, 32)*w_v;  oBv1 += __shfl(hBv1, fp, 32)*w_v;
    oAv2 += __shfl(hAv2, fp, 32)*w_v;  oBv2 += __shfl(hBv2, fp, 32)*w_v;
    oAps += __shfl(hAps, fp, 32)*w_p;  oBps += __shfl(hBps, fp, 32)*w_p;
    oAp0 += __shfl(hAp0, fp, 32)*w_q;  oBp0 += __shfl(hBp0, fp, 32)*w_q;
    oAp1 += __shfl(hAp1, fp, 32)*w_q;  oBp1 += __shfl(hBp1, fp, 32)*w_q;
    oAp2 += __shfl(hAp2, fp, 32)*w_q;  oBp2 += __shfl(hBp2, fp, 32)*w_q;
  }
  o_s[iA]=oAs; o_v[vA]=oAv0; o_v[vA+F_]=oAv1; o_v[vA+2*F_]=oAv2;
  o_ps[iA]=oAps; o_pv[vA]=oAp0; o_pv[vA+F_]=oAp1; o_pv[vA+2*F_]=oAp2;
  o_s[iB]=oBs; o_v[vB]=oBv0; o_v[vB+F_]=oBv1; o_v[vB+2*F_]=oBv2;
  o_ps[iB]=oBps; o_pv[vB]=oBp0; o_pv[vB+F_]=oBp1; o_pv[vB+2*F_]=oBp2;
  s[iA] += oAs;  s[iB] += oBs;
  v[vA] += oAv0; v[vA+F_] += oAv1; v[vA+2*F_] += oAv2;
  v[vB] += oBv0; v[vB+F_] += oBv1; v[vB+2*F_] += oBv2;
  ps[iA] += oAps; ps[iB] += oBps;
  pv[vA] += oAp0; pv[vA+F_] += oAp1; pv[vA+2*F_] += oAp2;
  pv[vB] += oBp0; pv[vB+F_] += oBp1; pv[vB+2*F_] += oBp2;
}

// ---------------- forward last (scalar) pass ----------------
__global__ __launch_bounds__(256) void edge_fwd_last_csr(
    const int* __restrict__ ord_d,
    const int* __restrict__ dst_off, const int* __restrict__ dst_perm,
    const int* __restrict__ src,
    const float* __restrict__ rd, const float* __restrict__ u3,
    const float* __restrict__ Wb0, const float* __restrict__ Wb1, const float* __restrict__ pwl,
    const float* __restrict__ s, const float* __restrict__ v, float* __restrict__ ys) {
  int gid = blockIdx.x * 256 + threadIdx.x;
  int n = ord_d[gid >> 5];
  int f = gid & 31;
  float wb0[K_], wb1[K_];
#pragma unroll
  for (int k = 0; k < K_; ++k) { wb0[k] = Wb0[k*F_+f]; wb1[k] = Wb1[k*F_+f]; }
  float p0 = pwl[f], p1 = pwl[F_+f];
  float m = 0.f;
  int j0 = dst_off[n], j1 = dst_off[n+1];
  for (int j = j0; j < j1; ++j) {
    int e = dst_perm[j];
    int ns = src[e];
    float radl = (f < K_) ? rd[(size_t)e*32 + f] : 0.f;
    float q0 = 0.f, q1 = 0.f;
#pragma unroll
    for (int k = 0; k < K_; ++k) {
      float rk = __shfl(radl, k, 32);
      q0 += rk * wb0[k];
      q1 += rk * wb1[k];
    }
    float u0 = u3[(size_t)e*3+0], u1 = u3[(size_t)e*3+1], u2 = u3[(size_t)e*3+2];
    float se = s[(size_t)ns*F_+f];
    size_t vb = (size_t)ns*3*F_;
    float vu = v[vb+f]*u0 + v[vb+F_+f]*u1 + v[vb+2*F_+f]*u2;
    m += p0*se*q0 + p1*vu*q1;
  }
  ys[(size_t)n*F_+f] = m;
}

__global__ __launch_bounds__(256) void node_fwd_last_kernel(
    float* __restrict__ s, const float* __restrict__ ys,
    const float* __restrict__ W1, const float* __restrict__ b1v,
    const float* __restrict__ W2, const float* __restrict__ b2v,
    float* __restrict__ a_l, const float* __restrict__ w_out,
    const float* __restrict__ ebias, const int* __restrict__ Z,
    const int* __restrict__ bseg, float* __restrict__ energy) {
  __shared__ float bins[B_];
  int tid = threadIdx.x;
  if (tid < B_) bins[tid] = 0.f;
  __syncthreads();
  int gid = blockIdx.x * 256 + tid;
  int n = gid >> 5, f = gid & 31;
  float y0 = s[gid] + ys[gid];
  float a = b1v[f];
#pragma unroll
  for (int fp = 0; fp < F_; ++fp) a += __shfl(y0, fp, 32) * W1[fp*F_+f];
  a_l[gid] = a;
  float g = sigm(a);
  float h = a * g;
  float o = b2v[f];
#pragma unroll
  for (int fp = 0; fp < F_; ++fp) o += __shfl(h, fp, 32) * W2[fp*F_+f];
  float sn = s[gid] + o;
  s[gid] = sn;
  float c = sn * w_out[f];
#pragma unroll
  for (int off = 16; off > 0; off >>= 1) c += __shfl_xor(c, off, 32);
  if (f == 0) {
    c += ebias[Z[n]];
    atomicAdd(&bins[bseg[n]], c);
  }
  __syncthreads();
  if (tid < B_) atomicAdd(&energy[tid], bins[tid]);
}

// ---------------- backward last (scalar) pass ----------------
__global__ __launch_bounds__(256) void b1_last_kernel(
    float* __restrict__ s, const float* __restrict__ a_l,
    const float* __restrict__ W1, const float* __restrict__ W2, const float* __restrict__ b2v,
    float* __restrict__ Gs, float* __restrict__ ys) {
  int gid = blockIdx.x * 256 + threadIdx.x;
  int f = gid & 31;
  float a = a_l[gid];
  float g = sigm(a);
  float h = a * g;
  float o = b2v[f];
#pragma unroll
  for (int fp = 0; fp < F_; ++fp) o += __shfl(h, fp, 32) * W2[fp*F_+f];
  s[gid] -= o;                       // reconstruct s_4
  float gso = Gs[gid];
  float gh = 0.f;
#pragma unroll
  for (int fp = 0; fp < F_; ++fp) gh += __shfl(gso, fp, 32) * W2[f*F_+fp];
  float ga = gh * (g + a*g*(1.f - g));
  float gy = 0.f;
#pragma unroll
  for (int fp = 0; fp < F_; ++fp) gy += __shfl(ga, fp, 32) * W1[f*F_+fp];
  ys[gid] = gy;
  Gs[gid] = gso + gy;
}

// merged backward last edge pass: 32 lanes per SRC node
__global__ __launch_bounds__(256) void b2m_last_kernel(
    const int* __restrict__ ord_s,
    const int* __restrict__ src_off, const int* __restrict__ src_perm,
    const int* __restrict__ dst,
    const float* __restrict__ rd, const float* __restrict__ u3,
    const float* __restrict__ Wb0, const float* __restrict__ Wb1, const float* __restrict__ pwl,
    const float* __restrict__ s, const float* __restrict__ v, const float* __restrict__ ysg,
    float* __restrict__ Gs, float* __restrict__ Gv,
    float* __restrict__ grad_r, float* __restrict__ grad_u) {
  int gid = blockIdx.x * 256 + threadIdx.x;
  int n = ord_s[gid >> 5];
  int f = gid & 31;
  float wb0[K_], wb1[K_];
#pragma unroll
  for (int k = 0; k < K_; ++k) { wb0[k] = Wb0[k*F_+f]; wb1[k] = Wb1[k*F_+f]; }
  float p0 = pwl[f], p1 = pwl[F_+f];
  size_t sb = (size_t)n*F_, svb = (size_t)n*3*F_;
  float se = s[sb+f];
  float ve0 = v[svb+f], ve1 = v[svb+F_+f], ve2 = v[svb+2*F_+f];
  float ags = 0.f, agv0 = 0.f, agv1 = 0.f, agv2 = 0.f;
  int j0 = src_off[n], j1 = src_off[n+1];
  for (int j = j0; j < j1; ++j) {
    int e = src_perm[j];
    int nd = dst[e];
    float rdl = rd[(size_t)e*32 + f];   // f<16: rad_f ; f>=16: drad_{f-16}
    float q0 = 0.f, q1 = 0.f, w0 = 0.f, w1 = 0.f;
#pragma unroll
    for (int k = 0; k < K_; ++k) {
      float rk = __shfl(rdl, k, 32);
      float dk = __shfl(rdl, k + 16, 32);
      q0 += rk * wb0[k]; q1 += rk * wb1[k];
      w0 += dk * wb0[k]; w1 += dk * wb1[k];
    }
    float u0 = u3[(size_t)e*3+0], u1 = u3[(size_t)e*3+1], u2 = u3[(size_t)e*3+2];
    float gm = ysg[(size_t)nd*F_+f];
    ags += p0*q0*gm;
    float t1 = p1*q1*gm;
    agv0 += t1*u0; agv1 += t1*u1; agv2 += t1*u2;
    float vu = ve0*u0 + ve1*u1 + ve2*u2;
    float gq0 = p0*se*gm;
    float gq1 = p1*vu*gm;
    float grl = gq0*w0 + gq1*w1;
    float gu0 = t1*ve0, gu1 = t1*ve1, gu2 = t1*ve2;
#pragma unroll
    for (int off = 16; off > 0; off >>= 1) {
      grl += __shfl_xor(grl, off, 32);
      gu0 += __shfl_xor(gu0, off, 32);
      gu1 += __shfl_xor(gu1, off, 32);
      gu2 += __shfl_xor(gu2, off, 32);
    }
    if (f == 0) grad_r[e] = grl;                  // first writer of the backward chain
    if (f < 3) grad_u[(size_t)e*3+f] = (f==0 ? gu0 : (f==1 ? gu1 : gu2));
  }
  Gs[sb+f] += ags;
  Gv[svb+f] += agv0; Gv[svb+F_+f] += agv1; Gv[svb+2*F_+f] += agv2;
}

// ---------------- backward node MLP: 2 nodes/thread, loads o_* (no fwd recompute) ----------------
__global__ __launch_bounds__(256) void b1_kernel(
    float* __restrict__ s, float* __restrict__ v, float* __restrict__ ps, float* __restrict__ pv,
    const float* __restrict__ a_s, const float* __restrict__ a_v,
    const float* __restrict__ a_ps, const float* __restrict__ a_pv,
    const float* __restrict__ o_s, const float* __restrict__ o_v,
    const float* __restrict__ o_ps, const float* __restrict__ o_pv,
    const float* __restrict__ W1, const float* __restrict__ W2,
    float* __restrict__ Gs, float* __restrict__ Gv, float* __restrict__ Gps, float* __restrict__ Gpv,
    float* __restrict__ ys, float* __restrict__ yv, float* __restrict__ yps, float* __restrict__ ypv) {
  int t = threadIdx.x;
  int f = t & 31, g = t >> 5;
  int nA = blockIdx.x * 16 + g;
  int nB = nA + 8;
  size_t iA = (size_t)nA*F_ + f, iB = (size_t)nB*F_ + f;
  size_t vA = (size_t)nA*3*F_ + f, vB = (size_t)nB*3*F_ + f;
  // reconstruct state from stored forward outputs
  s[iA] -= o_s[iA];  s[iB] -= o_s[iB];
  v[vA] -= o_v[vA];  v[vA+F_] -= o_v[vA+F_];  v[vA+2*F_] -= o_v[vA+2*F_];
  v[vB] -= o_v[vB];  v[vB+F_] -= o_v[vB+F_];  v[vB+2*F_] -= o_v[vB+2*F_];
  ps[iA] -= o_ps[iA]; ps[iB] -= o_ps[iB];
  pv[vA] -= o_pv[vA]; pv[vA+F_] -= o_pv[vA+F_]; pv[vA+2*F_] -= o_pv[vA+2*F_];
  pv[vB] -= o_pv[vB]; pv[vB+F_] -= o_pv[vB+F_]; pv[vB+2*F_] -= o_pv[vB+2*F_];
  // pre-gate activations
  float aAs=a_s[iA], aAv0=a_v[vA], aAv1=a_v[vA+F_], aAv2=a_v[vA+2*F_];
  float aAps=a_ps[iA], aAp0=a_pv[vA], aAp1=a_pv[vA+F_], aAp2=a_pv[vA+2*F_];
  float aBs=a_s[iB], aBv0=a_v[vB], aBv1=a_v[vB+F_], aBv2=a_v[vB+2*F_];
  float aBps=a_ps[iB], aBp0=a_pv[vB], aBp1=a_pv[vB+F_], aBp2=a_pv[vB+2*F_];
  float gA = sigm(aAs), gpA = gA*(1.f-gA);
  float gB = sigm(aBs), gpB = gB*(1.f-gB);
  // incoming grads
  float GAs=Gs[iA], GAv0=Gv[vA], GAv1=Gv[vA+F_], GAv2=Gv[vA+2*F_];
  float GAps=Gps[iA], GAp0=Gpv[vA], GAp1=Gpv[vA+F_], GAp2=Gpv[vA+2*F_];
  float GBs=Gs[iB], GBv0=Gv[vB], GBv1=Gv[vB+F_], GBv2=Gv[vB+2*F_];
  float GBps=Gps[iB], GBp0=Gpv[vB], GBp1=Gpv[vB+F_], GBp2=Gpv[vB+2*F_];
  const float* W2s = W2; const float* W2v = W2 + F_*F_;
  const float* W2p = W2 + 2*F_*F_; const float* W2q = W2 + 3*F_*F_;
  const float* W1s = W1; const float* W1v = W1 + F_*F_;
  const float* W1p = W1 + 2*F_*F_; const float* W1q = W1 + 3*F_*F_;
  // gh = G @ W2^T
  float hAs=0.f, hAv0=0.f, hAv1=0.f, hAv2=0.f, hAps=0.f, hAp0=0.f, hAp1=0.f, hAp2=0.f;
  float hBs=0.f, hBv0=0.f, hBv1=0.f, hBv2=0.f, hBps=0.f, hBp0=0.f, hBp1=0.f, hBp2=0.f;
#pragma unroll
  for (int fp = 0; fp < F_; ++fp) {
    float w_s = W2s[f*F_+fp], w_v = W2v[f*F_+fp], w_p = W2p[f*F_+fp], w_q = W2q[f*F_+fp];
    hAs  += __shfl(GAs, fp, 32)*w_s;   hBs  += __shfl(GBs, fp, 32)*w_s;
    hAv0 += __shfl(GAv0, fp, 32)*w_v;  hBv0 += __shfl(GBv0, fp, 32)*w_v;
    hAv1 += __shfl(GAv1, fp, 32)*w_v;  hBv1 += __shfl(GBv1, fp, 32)*w_v;
    hAv2 += __shfl(GAv2, fp, 32)*w_v;  hBv2 += __shfl(GBv2, fp, 32)*w_v;
    hAps += __shfl(GAps, fp, 32)*w_p;  hBps += __shfl(GBps, fp, 32)*w_p;
    hAp0 += __shfl(GAp0, fp, 32)*w_q;  hBp0 += __shfl(GBp0, fp, 32)*w_q;
    hAp1 += __shfl(GAp1, fp, 32)*w_q;  hBp1 += __shfl(GBp1, fp, 32)*w_q;
    hAp2 += __shfl(GAp2, fp, 32)*w_q;  hBp2 += __shfl(GBp2, fp, 32)*w_q;
  }
  // gate VJP
  float gasA = hAs*gA + (hAs*aAs + hAv0*aAv0 + hAv1*aAv1 + hAv2*aAv2 + hAps*aAps
                         + hAp0*aAp0 + hAp1*aAp1 + hAp2*aAp2) * gpA;
  float gasB = hBs*gB + (hBs*aBs + hBv0*aBv0 + hBv1*aBv1 + hBv2*aBv2 + hBps*aBps
                         + hBp0*aBp0 + hBp1*aBp1 + hBp2*aBp2) * gpB;
  float gAv0_=hAv0*gA, gAv1_=hAv1*gA, gAv2_=hAv2*gA, gAps_=hAps*gA;
  float gAp0_=hAp0*gA, gAp1_=hAp1*gA, gAp2_=hAp2*gA;
  float gBv0_=hBv0*gB, gBv1_=hBv1*gB, gBv2_=hBv2*gB, gBps_=hBps*gB;
  float gBp0_=hBp0*gB, gBp1_=hBp1*gB, gBp2_=hBp2*gB;
  // gy = ga @ W1^T
  float yAs=0.f, yAv0=0.f, yAv1=0.f, yAv2=0.f, yAps=0.f, yAp0=0.f, yAp1=0.f, yAp2=0.f;
  float yBs=0.f, yBv0=0.f, yBv1=0.f, yBv2=0.f, yBps=0.f, yBp0=0.f, yBp1=0.f, yBp2=0.f;
#pragma unroll
  for (int fp = 0; fp < F_; ++fp) {
    float w_s = W1s[f*F_+fp], w_v = W1v[f*F_+fp], w_p = W1p[f*F_+fp], w_q = W1q[f*F_+fp];
    yAs  += __shfl(gasA, fp, 32)*w_s;   yBs  += __shfl(gasB, fp, 32)*w_s;
    yAv0 += __shfl(gAv0_, fp, 32)*w_v;  yBv0 += __shfl(gBv0_, fp, 32)*w_v;
    yAv1 += __shfl(gAv1_, fp, 32)*w_v;  yBv1 += __shfl(gBv1_, fp, 32)*w_v;
    yAv2 += __shfl(gAv2_, fp, 32)*w_v;  yBv2 += __shfl(gBv2_, fp, 32)*w_v;
    yAps += __shfl(gAps_, fp, 32)*w_p;  yBps += __shfl(gBps_, fp, 32)*w_p;
    yAp0 += __shfl(gAp0_, fp, 32)*w_q;  yBp0 += __shfl(gBp0_, fp, 32)*w_q;
    yAp1 += __shfl(gAp1_, fp, 32)*w_q;  yBp1 += __shfl(gBp1_, fp, 32)*w_q;
    yAp2 += __shfl(gAp2_, fp, 32)*w_q;  yBp2 += __shfl(gBp2_, fp, 32)*w_q;
  }
  ys[iA]=yAs; yv[vA]=yAv0; yv[vA+F_]=yAv1; yv[vA+2*F_]=yAv2;
  yps[iA]=yAps; ypv[vA]=yAp0; ypv[vA+F_]=yAp1; ypv[vA+2*F_]=yAp2;
  ys[iB]=yBs; yv[vB]=yBv0; yv[vB+F_]=yBv1; yv[vB+2*F_]=yBv2;
  yps[iB]=yBps; ypv[vB]=yBp0; ypv[vB+F_]=yBp1; ypv[vB+2*F_]=yBp2;
  Gs[iA]=GAs+yAs; Gv[vA]=GAv0+yAv0; Gv[vA+F_]=GAv1+yAv1; Gv[vA+2*F_]=GAv2+yAv2;
  Gps[iA]=GAps+yAps; Gpv[vA]=GAp0+yAp0; Gpv[vA+F_]=GAp1+yAp1; Gpv[vA+2*F_]=GAp2+yAp2;
  Gs[iB]=GBs+yBs; Gv[vB]=GBv0+yBv0; Gv[vB+F_]=GBv1+yBv1; Gv[vB+2*F_]=GBv2+yBv2;
  Gps[iB]=GBps+yBps; Gpv[vB]=GBp0+yBp0; Gpv[vB+F_]=GBp1+yBp1; Gpv[vB+2*F_]=GBp2+yBp2;
}

// ---------------- merged backward edge pass: 32 lanes per SRC node ----------------
__global__ __launch_bounds__(256) void b2m_kernel(
    const int* __restrict__ ord_s,
    const int* __restrict__ src_off, const int* __restrict__ src_perm,
    const int* __restrict__ dst,
    const float* __restrict__ rd, const float* __restrict__ u3,
    const float* __restrict__ Wb0, const float* __restrict__ Wb1, const float* __restrict__ pw,
    const float* __restrict__ s, const float* __restrict__ v,
    const float* __restrict__ ps, const float* __restrict__ pv,
    const float* __restrict__ ys, const float* __restrict__ yv,
    const float* __restrict__ yps, const float* __restrict__ ypv,
    float* __restrict__ Gs, float* __restrict__ Gv, float* __restrict__ Gps, float* __restrict__ Gpv,
    float* __restrict__ grad_r, float* __restrict__ grad_u) {
  int gid = blockIdx.x * 256 + threadIdx.x;
  int n = ord_s[gid >> 5];
  int f = gid & 31;
  float wb0[K_], wb1[K_];
#pragma unroll
  for (int k = 0; k < K_; ++k) { wb0[k] = Wb0[k*F_+f]; wb1[k] = Wb1[k*F_+f]; }
  float pw0=pw[f],      pw1=pw[F_+f],   pw2=pw[2*F_+f], pw3=pw[3*F_+f], pw4=pw[4*F_+f];
  float pw5=pw[5*F_+f], pw6=pw[6*F_+f], pw7=pw[7*F_+f], pw8=pw[8*F_+f], pw9=pw[9*F_+f];
  size_t sb = (size_t)n*F_, svb = (size_t)n*3*F_;
  float se = s[sb+f], pse = ps[sb+f];
  float ve0 = v[svb+f], ve1 = v[svb+F_+f], ve2 = v[svb+2*F_+f];
  float pve0 = pv[svb+f], pve1 = pv[svb+F_+f], pve2 = pv[svb+2*F_+f];
  float ase=0.f, apse=0.f;
  float ave0=0.f, ave1=0.f, ave2=0.f, apve0=0.f, apve1=0.f, apve2=0.f;
  int j0 = src_off[n], j1 = src_off[n+1];
  for (int j = j0; j < j1; ++j) {
    int e = src_perm[j];
    int nd = dst[e];
    float rdl = rd[(size_t)e*32 + f];
    float q0 = 0.f, q1 = 0.f, w0 = 0.f, w1 = 0.f;
#pragma unroll
    for (int k = 0; k < K_; ++k) {
      float rk = __shfl(rdl, k, 32);
      float dk = __shfl(rdl, k + 16, 32);
      q0 += rk * wb0[k]; q1 += rk * wb1[k];
      w0 += dk * wb0[k]; w1 += dk * wb1[k];
    }
    float u0 = u3[(size_t)e*3+0], u1 = u3[(size_t)e*3+1], u2 = u3[(size_t)e*3+2];
    size_t db = (size_t)nd*F_, dvb = (size_t)nd*3*F_;
    float gms = ys[db+f];
    float gmv0 = yv[dvb+f], gmv1 = yv[dvb+F_+f], gmv2 = yv[dvb+2*F_+f];
    float gmps = yps[db+f];
    float gmpv0 = ypv[dvb+f], gmpv1 = ypv[dvb+F_+f], gmpv2 = ypv[dvb+2*F_+f];
    float udgmv  = u0*gmv0 + u1*gmv1 + u2*gmv2;
    float udgmpv = u0*gmpv0 + u1*gmpv1 + u2*gmpv2;
    float uxgmpv0 = u1*gmpv2 - u2*gmpv1, uxgmpv1 = u2*gmpv0 - u0*gmpv2, uxgmpv2 = u0*gmpv1 - u1*gmpv0;
    float uxgmv0  = u1*gmv2 - u2*gmv1,   uxgmv1  = u2*gmv0 - u0*gmv2,   uxgmv2  = u0*gmv1 - u1*gmv0;
    // own-state (source) grads — accumulate locally
    ase  += pw0*q0*gms  + pw5*q1*udgmv;
    apse += pw2*q0*gmps + pw8*q1*udgmpv;
    ave0 += pw1*u0*q1*gms + pw4*q0*gmv0 + pw9*q1*uxgmpv0;
    ave1 += pw1*u1*q1*gms + pw4*q0*gmv1 + pw9*q1*uxgmpv1;
    ave2 += pw1*u2*q1*gms + pw4*q0*gmv2 + pw9*q1*uxgmpv2;
    apve0 += pw3*u0*q1*gmps + pw7*q0*gmpv0 + pw6*q1*uxgmv0;
    apve1 += pw3*u1*q1*gmps + pw7*q0*gmpv1 + pw6*q1*uxgmv1;
    apve2 += pw3*u2*q1*gmps + pw7*q0*gmpv2 + pw6*q1*uxgmv2;
    // basis grads (need own state x dst grads)
    float vu  = ve0*u0 + ve1*u1 + ve2*u2;
    float pvu = pve0*u0 + pve1*u1 + pve2*u2;
    float cpu0 = pve1*u2 - pve2*u1, cpu1 = pve2*u0 - pve0*u2, cpu2 = pve0*u1 - pve1*u0;
    float cvu0 = ve1*u2 - ve2*u1,  cvu1 = ve2*u0 - ve0*u2,  cvu2 = ve0*u1 - ve1*u0;
    float gq0 = pw0*se*gms + pw2*pse*gmps
              + pw4*(ve0*gmv0 + ve1*gmv1 + ve2*gmv2)
              + pw7*(pve0*gmpv0 + pve1*gmpv1 + pve2*gmpv2);
    float gq1 = pw1*vu*gms + pw3*pvu*gmps + pw5*se*udgmv
              + pw6*(cpu0*gmv0 + cpu1*gmv1 + cpu2*gmv2)
              + pw8*pse*udgmpv
              + pw9*(cvu0*gmpv0 + cvu1*gmpv1 + cvu2*gmpv2);
    float grl = gq0*w0 + gq1*w1;   // dL/dr contribution (projected through drad)
    float gmvxpve0 = gmv1*pve2 - gmv2*pve1, gmvxpve1 = gmv2*pve0 - gmv0*pve2, gmvxpve2 = gmv0*pve1 - gmv1*pve0;
    float gmpvxve0 = gmpv1*ve2 - gmpv2*ve1, gmpvxve1 = gmpv2*ve0 - gmpv0*ve2, gmpvxve2 = gmpv0*ve1 - gmpv1*ve0;
    float gu0 = q1*(pw1*gms*ve0 + pw3*gmps*pve0 + pw5*se*gmv0 + pw6*gmvxpve0 + pw8*pse*gmpv0 + pw9*gmpvxve0);
    float gu1 = q1*(pw1*gms*ve1 + pw3*gmps*pve1 + pw5*se*gmv1 + pw6*gmvxpve1 + pw8*pse*gmpv1 + pw9*gmpvxve1);
    float gu2 = q1*(pw1*gms*ve2 + pw3*gmps*pve2 + pw5*se*gmv2 + pw6*gmvxpve2 + pw8*pse*gmpv2 + pw9*gmpvxve2);
#pragma unroll
    for (int off = 16; off > 0; off >>= 1) {
      grl += __shfl_xor(grl, off, 32);
      gu0 += __shfl_xor(gu0, off, 32);
      gu1 += __shfl_xor(gu1, off, 32);
      gu2 += __shfl_xor(gu2, off, 32);
    }
    if (f == 0) grad_r[e] += grl;
    if (f < 3) grad_u[(size_t)e*3+f] += (f==0 ? gu0 : (f==1 ? gu1 : gu2));
  }
  Gs[sb+f]  += ase;
  Gps[sb+f] += apse;
  Gv[svb+f] += ave0;  Gv[svb+F_+f] += ave1;  Gv[svb+2*F_+f] += ave2;
  Gpv[svb+f] += apve0; Gpv[svb+F_+f] += apve1; Gpv[svb+2*F_+f] += apve2;
}

// ---------------- basis backward: (grad_r, grad_u) -> forces ----------------
__global__ void basis_bwd_kernel(const int* __restrict__ dst, const int* __restrict__ src,
                                 const float* __restrict__ rr, const float* __restrict__ u3,
                                 const float* __restrict__ grad_r, const float* __restrict__ grad_u,
                                 float* __restrict__ forces) {
  int e = blockIdx.x * blockDim.x + threadIdx.x;
  if (e >= E_) return;
  float r = rr[e];
  float u0 = u3[(size_t)e*3+0], u1 = u3[(size_t)e*3+1], u2 = u3[(size_t)e*3+2];
  float gr = grad_r[e];
  float g0 = grad_u[(size_t)e*3+0], g1 = grad_u[(size_t)e*3+1], g2 = grad_u[(size_t)e*3+2];
  float gdu = g0*u0 + g1*u1 + g2*u2;
  float invr = 1.f / r;
  float gd0 = gr*u0 + (g0 - gdu*u0)*invr;
  float gd1 = gr*u1 + (g1 - gdu*u1)*invr;
  float gd2 = gr*u2 + (g2 - gdu*u2)*invr;
  int ns = src[e], nd = dst[e];
  atomicAdd(&forces[(size_t)ns*3+0], gd0);
  atomicAdd(&forces[(size_t)ns*3+1], gd1);
  atomicAdd(&forces[(size_t)ns*3+2], gd2);
  atomicAdd(&forces[(size_t)nd*3+0], -gd0);
  atomicAdd(&forces[(size_t)nd*3+1], -gd1);
  atomicAdd(&forces[(size_t)nd*3+2], -gd2);
}

// ---------------- host launcher ----------------
extern "C" void kernel_launch(void* const* d_in, const int* in_sizes, int n_in,
                              void* d_out, int out_size, void* d_ws, size_t ws_size,
                              hipStream_t stream) {
  const int*   Z     = (const int*)d_in[0];
  const float* pos   = (const float*)d_in[1];
  const int*   dst   = (const int*)d_in[2];
  const int*   src   = (const int*)d_in[3];
  const int*   bseg  = (const int*)d_in[4];
  const float* embed = (const float*)d_in[6];
  const float* Wb0   = (const float*)d_in[7];
  const float* Wb1   = (const float*)d_in[8];
  const float* pw    = (const float*)d_in[9];
  const float* Wd1   = (const float*)d_in[10];
  const float* bd1   = (const float*)d_in[11];
  const float* Wd2   = (const float*)d_in[12];
  const float* bd2   = (const float*)d_in[13];
  const float* Wb0l  = (const float*)d_in[14];
  const float* Wb1l  = (const float*)d_in[15];
  const float* pwl   = (const float*)d_in[16];
  const float* Wd1l  = (const float*)d_in[17];
  const float* bd1l  = (const float*)d_in[18];
  const float* Wd2l  = (const float*)d_in[19];
  const float* bd2l  = (const float*)d_in[20];
  const float* w_out = (const float*)d_in[21];
  const float* ebias = (const float*)d_in[22];

  float* out = (float*)d_out;
  float* energy = out;          // (B,)
  float* forces = out + B_;     // (N,3)

  float* ws = nullptr;
  (void)hipGetSymbolAddress((void**)&ws, HIP_SYMBOL(g_ws));

  const size_t NF = (size_t)N_ * F_;
  const size_t NV = (size_t)N_ * 3 * F_;
  float* rd       = ws;                       // E*32 (rad | drad)
  float* u3       = rd + (size_t)E_*32;       // E*3
  float* rr       = u3 + (size_t)E_*3;        // E
  float* s        = rr + E_;                  // N*F
  float* v        = s + NF;                   // N*3F
  float* ps       = v + NV;                   // N*F
  float* pv       = ps + NF;                  // N*3F
  float* ys       = pv + NV;                  // N*F
  float* yv       = ys + NF;                  // N*3F
  float* yps      = yv + NV;                  // N*F
  float* ypv      = yps + NF;                 // N*3F
  float* Gs       = ypv + NV;                 // N*F
  float* Gv       = Gs + NF;                  // N*3F
  float* Gps      = Gv + NV;                  // N*F
  float* Gpv      = Gps + NF;                 // N*3F
  float* grad_r   = Gpv + NV;                 // E
  float* grad_u   = grad_r + E_;              // E*3
  float* a_s      = grad_u + (size_t)E_*3;    // 4*N*F
  float* a_v      = a_s + 4*NF;               // 4*N*3F
  float* a_ps     = a_v + 4*NV;               // 4*N*F
  float* a_pv     = a_ps + 4*NF;              // 4*N*3F
  float* o_s      = a_pv + 4*NV;              // 4*N*F
  float* o_v      = o_s + 4*NF;               // 4*N*3F
  float* o_ps     = o_v + 4*NV;               // 4*N*F
  float* o_pv     = o_ps + 4*NF;              // 4*N*3F
  float* a_l      = o_pv + 4*NV;              // N*F
  // int region (CSR + sort)
  int* iws        = (int*)(a_l + NF);
  int* cntd       = iws;                      // N
  int* cnts       = cntd + N_;                // N
  int* dst_off    = cnts + N_;                // N+1
  int* src_off    = dst_off + (N_+1);         // N+1
  int* dst_perm   = src_off + (N_+1);         // E
  int* src_perm   = dst_perm + E_;            // E
  int* curd       = src_perm + E_;            // N
  int* curs       = curd + N_;                // N
  int* binc       = curs + N_;                // 128
  int* bcur       = binc + 128;               // 128
  int* ord_d      = bcur + 128;               // N
  int* ord_s      = ord_d + N_;               // N

  const int TB = 256;
  const int nodeBlocks = (int)(NF / TB);             // 6250 (CSR + per-channel node kernels)
  const int nodeBlocks2 = N_ / 16;                   // 3125 (2-node/thread MLP kernels)
  const int eThreadBlocks = (E_ + TB - 1) / TB;      // 1563
  const int nThreadBlocks = (N_ + TB - 1) / TB;      // 196

  // ---- CSR build + degree sort ----
  fill_int_kernel<<<256, TB, 0, stream>>>(cntd, (size_t)2*N_, 0);
  fill_int_kernel<<<1, 128, 0, stream>>>(binc, 128, 0);
  hist_kernel<<<eThreadBlocks, TB, 0, stream>>>(dst, src, cntd, cnts);
  scan_kernel<<<2, 1024, 0, stream>>>(cntd, cnts, dst_off, src_off);
  cursor_init_kernel<<<nThreadBlocks, TB, 0, stream>>>(dst_off, src_off, curd, curs);
  scatter_kernel<<<eThreadBlocks, TB, 0, stream>>>(dst, src, curd, curs, dst_perm, src_perm);
  sort_hist_kernel<<<nThreadBlocks, TB, 0, stream>>>(dst_off, src_off, binc);
  sort_scan_kernel<<<1, 64, 0, stream>>>(binc, bcur);
  sort_scatter_kernel<<<nThreadBlocks, TB, 0, stream>>>(dst_off, src_off, bcur, ord_d, ord_s);

  // ---- init state + geometry ----
  fill_kernel<<<2048, TB, 0, stream>>>(v, 7*NF, 0.f);  // v,ps,pv = 0
  init_embed_kernel<<<nodeBlocks, TB, 0, stream>>>(s, embed, Z);
  geom_kernel<<<eThreadBlocks, TB, 0, stream>>>(pos, dst, src, rd, u3, rr);

  // ---- 4 full equivariant passes ----
  for (int i = 0; i < 4; ++i) {
    edge_fwd_csr<<<nodeBlocks, TB, 0, stream>>>(
        ord_d, dst_off, dst_perm, src, rd, u3,
        Wb0 + (size_t)i*K_*F_, Wb1 + (size_t)i*K_*F_, pw + (size_t)i*10*F_,
        s, v, ps, pv, ys, yv, yps, ypv);
    node_fwd_kernel<<<nodeBlocks2, TB, 0, stream>>>(
        s, v, ps, pv, ys, yv, yps, ypv,
        Wd1 + (size_t)i*4*F_*F_, bd1 + (size_t)i*F_,
        Wd2 + (size_t)i*4*F_*F_, bd2 + (size_t)i*F_,
        a_s + i*NF, a_v + i*NV, a_ps + i*NF, a_pv + i*NV,
        o_s + i*NF, o_v + i*NV, o_ps + i*NF, o_pv + i*NV);
  }

  // ---- last scalar pass ----
  fill_kernel<<<592, TB, 0, stream>>>(out, (size_t)(B_ + N_*3), 0.f);
  edge_fwd_last_csr<<<nodeBlocks, TB, 0, stream>>>(
      ord_d, dst_off, dst_perm, src, rd, u3, Wb0l, Wb1l, pwl, s, v, ys);
  node_fwd_last_kernel<<<nodeBlocks, TB, 0, stream>>>(
      s, ys, Wd1l, bd1l, Wd2l, bd2l, a_l, w_out, ebias, Z, bseg, energy);

  // ---- backward init ----
  init_gs_kernel<<<nodeBlocks, TB, 0, stream>>>(Gs, w_out);
  fill_kernel<<<2048, TB, 0, stream>>>(Gv, 7*NF, 0.f);

  // ---- last pass backward (writes grad_r/grad_u, no fill needed) ----
  b1_last_kernel<<<nodeBlocks, TB, 0, stream>>>(s, a_l, Wd1l, Wd2l, bd2l, Gs, ys);
  b2m_last_kernel<<<nodeBlocks, TB, 0, stream>>>(
      ord_s, src_off, src_perm, dst, rd, u3, Wb0l, Wb1l, pwl, s, v, ys,
      Gs, Gv, grad_r, grad_u);

  // ---- 4 full passes backward ----
  for (int i = 3; i >= 0; --i) {
    b1_kernel<<<nodeBlocks2, TB, 0, stream>>>(
        s, v, ps, pv,
        a_s + i*NF, a_v + i*NV, a_ps + i*NF, a_pv + i*NV,
        o_s + i*NF, o_v + i*NV, o_ps + i*NF, o_pv + i*NV,
        Wd1 + (size_t)i*4*F_*F_, Wd2 + (size_t)i*4*F_*F_,
        Gs, Gv, Gps, Gpv, ys, yv, yps, ypv);
    b2m_kernel<<<nodeBlocks, TB, 0, stream>>>(
        ord_s, src_off, src_perm, dst, rd, u3,
        Wb0 + (size_t)i*K_*F_, Wb1 + (size_t)i*K_*F_, pw + (size_t)i*10*F_,
        s, v, ps, pv, ys, yv, yps, ypv, Gs, Gv, Gps, Gpv, grad_r, grad_u);
  }

  // ---- basis backward -> forces ----
  basis_bwd_kernel<<<eThreadBlocks, TB, 0, stream>>>(
      dst, src, rr, u3, grad_r, grad_u, forces);
}